// Round 4
// baseline (432.653 us; speedup 1.0000x reference)
//
#include <hip/hip_runtime.h>

#define N_NODES 8192
#define IN_DIM  128
#define HDIM    256
#define NEDGE   131072

typedef unsigned short ushort_t;
typedef __bf16 bf16x8 __attribute__((ext_vector_type(8)));
typedef float  f32x4  __attribute__((ext_vector_type(4)));

__device__ inline ushort_t f32_to_bf16_rn(float f) {
    unsigned u = __builtin_bit_cast(unsigned, f);
    u += 0x7fffu + ((u >> 16) & 1u);
    return (ushort_t)(u >> 16);
}
__device__ inline float bf16_bits_to_f32(ushort_t h) {
    unsigned u = ((unsigned)h) << 16;
    return __builtin_bit_cast(float, u);
}
__device__ inline void split_bf16(float f, ushort_t& hi, ushort_t& lo) {
    hi = f32_to_bf16_rn(f);
    float rem = f - bf16_bits_to_f32(hi);
    lo = f32_to_bf16_rn(rem);
}
__device__ inline float recon(ushort_t h, ushort_t l) {
    return bf16_bits_to_f32(h) + bf16_bits_to_f32(l);
}

// ================= CSR build =================
__global__ void hist_kernel(const int* __restrict__ dst, int* __restrict__ deg) {
    int e = blockIdx.x * blockDim.x + threadIdx.x;
    if (e < NEDGE) atomicAdd(&deg[dst[e]], 1);
}

__global__ __launch_bounds__(1024) void build_scan(const int* __restrict__ deg,
                                                   int* __restrict__ offs,
                                                   int* __restrict__ cursor) {
    __shared__ int part[1024];
    int t = threadIdx.x;
    int base = t * 8;
    int local[8];
    int s = 0;
#pragma unroll
    for (int i = 0; i < 8; ++i) { local[i] = s; s += deg[base + i]; }
    part[t] = s;
    __syncthreads();
    for (int off = 1; off < 1024; off <<= 1) {
        int v = (t >= off) ? part[t - off] : 0;
        __syncthreads();
        part[t] += v;
        __syncthreads();
    }
    int prefix = (t == 0) ? 0 : part[t - 1];
#pragma unroll
    for (int i = 0; i < 8; ++i) {
        int o = prefix + local[i];
        offs[base + i] = o;
        cursor[base + i] = o;
    }
    if (t == 1023) offs[N_NODES] = part[1023];
}

__global__ void fill_kernel(const int* __restrict__ src, const int* __restrict__ dst,
                            int* __restrict__ cursor, int* __restrict__ bucket) {
    int e = blockIdx.x * blockDim.x + threadIdx.x;
    if (e >= NEDGE) return;
    int p = atomicAdd(&cursor[dst[e]], 1);
    bucket[p] = src[e];
}

// ================= weight prep: transpose + hi/lo split =================
// th[n*K+k] = bf16_hi(w[k*N+n]), tl = residual
__global__ void prep_wsplit(const float* __restrict__ w, int K, int N,
                            ushort_t* __restrict__ th, ushort_t* __restrict__ tl) {
    int id = blockIdx.x * 256 + threadIdx.x;
    if (id >= K * N) return;
    int n = id / K, k = id - n * K;
    float f = w[(size_t)k * N + n];
    ushort_t hb, lb;
    split_bf16(f, hb, lb);
    th[id] = hb; tl[id] = lb;
}

// ================= aggregation =================
// D=128: reads f32 x, writes hi/lo pair
__global__ __launch_bounds__(256) void aggregate128_split(
    const float* __restrict__ x, const int* __restrict__ offs,
    const int* __restrict__ bucket, ushort_t* __restrict__ hh, ushort_t* __restrict__ hl) {
    int lane = threadIdx.x & 63;
    int node = blockIdx.x * 4 + (threadIdx.x >> 6);
    const float2* x2 = reinterpret_cast<const float2*>(x);
    float2 acc = x2[(size_t)node * 64 + lane];
    int b = offs[node], e = offs[node + 1];
    int k = b;
    for (; k + 1 < e; k += 2) {
        int s0 = bucket[k], s1 = bucket[k + 1];
        float2 v0 = x2[(size_t)s0 * 64 + lane];
        float2 v1 = x2[(size_t)s1 * 64 + lane];
        acc.x += v0.x + v1.x; acc.y += v0.y + v1.y;
    }
    if (k < e) {
        float2 v0 = x2[(size_t)bucket[k] * 64 + lane];
        acc.x += v0.x; acc.y += v0.y;
    }
    ushort2 h2, l2;
    split_bf16(acc.x, h2.x, l2.x);
    split_bf16(acc.y, h2.y, l2.y);
    reinterpret_cast<ushort2*>(hh)[(size_t)node * 64 + lane] = h2;
    reinterpret_cast<ushort2*>(hl)[(size_t)node * 64 + lane] = l2;
}

// D=256: reads hi/lo pair, writes hi/lo pair
__global__ __launch_bounds__(256) void aggregate256_split(
    const ushort_t* __restrict__ xh, const ushort_t* __restrict__ xl,
    const int* __restrict__ offs, const int* __restrict__ bucket,
    ushort_t* __restrict__ hh, ushort_t* __restrict__ hl) {
    int lane = threadIdx.x & 63;
    int node = blockIdx.x * 4 + (threadIdx.x >> 6);
    const ushort4* x4h = reinterpret_cast<const ushort4*>(xh);
    const ushort4* x4l = reinterpret_cast<const ushort4*>(xl);
    ushort4 sh = x4h[(size_t)node * 64 + lane];
    ushort4 sl = x4l[(size_t)node * 64 + lane];
    float4 acc = { recon(sh.x, sl.x), recon(sh.y, sl.y), recon(sh.z, sl.z), recon(sh.w, sl.w) };
    int b = offs[node], e = offs[node + 1];
    for (int k = b; k < e; ++k) {
        size_t s = (size_t)bucket[k] * 64 + lane;
        ushort4 vh = x4h[s];
        ushort4 vl = x4l[s];
        acc.x += recon(vh.x, vl.x);
        acc.y += recon(vh.y, vl.y);
        acc.z += recon(vh.z, vl.z);
        acc.w += recon(vh.w, vl.w);
    }
    ushort4 oh, ol;
    split_bf16(acc.x, oh.x, ol.x);
    split_bf16(acc.y, oh.y, ol.y);
    split_bf16(acc.z, oh.z, ol.z);
    split_bf16(acc.w, oh.w, ol.w);
    reinterpret_cast<ushort4*>(hh)[(size_t)node * 64 + lane] = oh;
    reinterpret_cast<ushort4*>(hl)[(size_t)node * 64 + lane] = ol;
}

// ================= split-bf16 MFMA GEMM =================
// C[M,256] = relu(A[M,K] @ B[K,256] + bias); A as hi/lo [M][K], B as hi/lo transposed [256][K]
// wave tile 32x32 (2x2 frags of 16x16x32), block 64x64, grid (M/64, 256/64)
template<int K>
__global__ __launch_bounds__(256, 2) void gemm_mfma(
    const ushort_t* __restrict__ Ah, const ushort_t* __restrict__ Al,
    const ushort_t* __restrict__ Bh, const ushort_t* __restrict__ Bl,
    const float* __restrict__ bias,
    ushort_t* __restrict__ Ch, ushort_t* __restrict__ Cl) {
    const int tid = threadIdx.x;
    const int w = tid >> 6, lane = tid & 63;
    const int m0 = blockIdx.x * 64 + (w >> 1) * 32;
    const int n0 = blockIdx.y * 64 + (w & 1) * 32;
    const int lr = lane & 15;          // A row / B col / C col within frag
    const int kq = (lane >> 4) * 8;    // k-slice base within frag
    f32x4 acc[2][2] = {};
#pragma unroll
    for (int ks = 0; ks < K; ks += 32) {
        bf16x8 ah[2], al[2], bh[2], bl[2];
#pragma unroll
        for (int mi = 0; mi < 2; ++mi) {
            size_t off = (size_t)(m0 + mi * 16 + lr) * K + ks + kq;
            ah[mi] = *reinterpret_cast<const bf16x8*>(Ah + off);
            al[mi] = *reinterpret_cast<const bf16x8*>(Al + off);
        }
#pragma unroll
        for (int ni = 0; ni < 2; ++ni) {
            size_t off = (size_t)(n0 + ni * 16 + lr) * K + ks + kq;
            bh[ni] = *reinterpret_cast<const bf16x8*>(Bh + off);
            bl[ni] = *reinterpret_cast<const bf16x8*>(Bl + off);
        }
#pragma unroll
        for (int mi = 0; mi < 2; ++mi)
#pragma unroll
            for (int ni = 0; ni < 2; ++ni) {
                acc[mi][ni] = __builtin_amdgcn_mfma_f32_16x16x32_bf16(ah[mi], bh[ni], acc[mi][ni], 0, 0, 0);
                acc[mi][ni] = __builtin_amdgcn_mfma_f32_16x16x32_bf16(ah[mi], bl[ni], acc[mi][ni], 0, 0, 0);
                acc[mi][ni] = __builtin_amdgcn_mfma_f32_16x16x32_bf16(al[mi], bh[ni], acc[mi][ni], 0, 0, 0);
            }
    }
    // epilogue: bias + relu + split + store (C/D frag: col=lane&15, row=(lane>>4)*4+reg)
    float bc[2] = { bias[n0 + lr], bias[n0 + 16 + lr] };
    const int rbase = (lane >> 4) * 4;
#pragma unroll
    for (int mi = 0; mi < 2; ++mi)
#pragma unroll
        for (int ni = 0; ni < 2; ++ni)
#pragma unroll
            for (int r = 0; r < 4; ++r) {
                float v = acc[mi][ni][r] + bc[ni];
                v = fmaxf(v, 0.f);
                ushort_t hb, lb;
                split_bf16(v, hb, lb);
                int row = m0 + mi * 16 + rbase + r;
                int col = n0 + ni * 16 + lr;
                size_t o = (size_t)row * HDIM + col;
                Ch[o] = hb;
                Cl[o] = lb;
            }
}

// ================= edge head: fold w_out =================
__global__ void prep_vec(const float* __restrict__ w_out, const float* __restrict__ b_out,
                         const float* __restrict__ w_edge, const float* __restrict__ b_edge,
                         float* __restrict__ v) {
    int c = threadIdx.x;  // 256 threads
    float sa = 0.f, sb = 0.f;
    for (int k = 0; k < HDIM; k += 4) {
        float4 w  = *reinterpret_cast<const float4*>(&w_out[(size_t)c * HDIM + k]);
        float4 ua = *reinterpret_cast<const float4*>(&w_edge[k]);
        float4 ub = *reinterpret_cast<const float4*>(&w_edge[HDIM + k]);
        sa += w.x * ua.x + w.y * ua.y + w.z * ua.z + w.w * ua.w;
        sb += w.x * ub.x + w.y * ub.y + w.z * ub.z + w.w * ub.w;
    }
    v[c] = sa;
    v[HDIM + c] = sb;
    __shared__ float ra[HDIM], rb[HDIM];
    ra[c] = b_out[c] * w_edge[c];
    rb[c] = b_out[c] * w_edge[HDIM + c];
    __syncthreads();
    for (int s = 128; s > 0; s >>= 1) {
        if (c < s) { ra[c] += ra[c + s]; rb[c] += rb[c + s]; }
        __syncthreads();
    }
    if (c == 0) { v[512] = ra[0] + b_edge[0]; v[513] = rb[0]; }
}

__global__ void lilj_kernel(const ushort_t* __restrict__ xh, const ushort_t* __restrict__ xl,
                            const float* __restrict__ v,
                            float* __restrict__ li, float* __restrict__ lj) {
    int lane = threadIdx.x & 63;
    int node = blockIdx.x * 4 + (threadIdx.x >> 6);
    ushort4 h4 = reinterpret_cast<const ushort4*>(xh)[(size_t)node * 64 + lane];
    ushort4 l4 = reinterpret_cast<const ushort4*>(xl)[(size_t)node * 64 + lane];
    float4 xa = { recon(h4.x, l4.x), recon(h4.y, l4.y), recon(h4.z, l4.z), recon(h4.w, l4.w) };
    float4 va = reinterpret_cast<const float4*>(v)[lane];
    float4 vb = reinterpret_cast<const float4*>(v + HDIM)[lane];
    float a = xa.x * va.x + xa.y * va.y + xa.z * va.z + xa.w * va.w;
    float b = xa.x * vb.x + xa.y * vb.y + xa.z * vb.z + xa.w * vb.w;
#pragma unroll
    for (int off = 32; off > 0; off >>= 1) {
        a += __shfl_down(a, off);
        b += __shfl_down(b, off);
    }
    if (lane == 0) {
        li[node] = a + v[512];
        lj[node] = b + v[513];
    }
}

__global__ void edge_out(const float* __restrict__ li, const float* __restrict__ lj,
                         float* __restrict__ out) {
    int i = blockIdx.y;
    int j4 = blockIdx.x * blockDim.x + threadIdx.x;
    float a = li[i];
    float4 b = reinterpret_cast<const float4*>(lj)[j4];
    float4 r = {a + b.x, a + b.y, a + b.z, a + b.w};
    reinterpret_cast<float4*>(out)[(size_t)i * (N_NODES / 4) + j4] = r;
}

extern "C" void kernel_launch(void* const* d_in, const int* in_sizes, int n_in,
                              void* d_out, int out_size, void* d_ws, size_t ws_size,
                              hipStream_t stream) {
    const float* x      = (const float*)d_in[0];
    const int*   ei     = (const int*)d_in[1];
    const float* w0a    = (const float*)d_in[2];
    const float* b0a    = (const float*)d_in[3];
    const float* w0b    = (const float*)d_in[4];
    const float* b0b    = (const float*)d_in[5];
    const float* w1a    = (const float*)d_in[6];
    const float* b1a    = (const float*)d_in[7];
    const float* w1b    = (const float*)d_in[8];
    const float* b1b    = (const float*)d_in[9];
    const float* w_out  = (const float*)d_in[10];
    const float* b_out  = (const float*)d_in[11];
    const float* w_edge = (const float*)d_in[12];
    const float* b_edge = (const float*)d_in[13];
    const int* src = ei;
    const int* dst = ei + NEDGE;

    // ---- ws carve (ushort region first; all sizes multiples of 64KB keep 16B alignment) ----
    ushort_t* us = (ushort_t*)d_ws;
    ushort_t* h0h = us;                       us += (size_t)N_NODES * IN_DIM;   // 1M
    ushort_t* h0l = us;                       us += (size_t)N_NODES * IN_DIM;
    ushort_t* th_ = us;                       us += (size_t)N_NODES * HDIM;     // 2M
    ushort_t* tl_ = us;                       us += (size_t)N_NODES * HDIM;
    ushort_t* x1h = us;                       us += (size_t)N_NODES * HDIM;
    ushort_t* x1l = us;                       us += (size_t)N_NODES * HDIM;
    ushort_t* h1h = us;                       us += (size_t)N_NODES * HDIM;
    ushort_t* h1l = us;                       us += (size_t)N_NODES * HDIM;
    ushort_t* x2h = us;                       us += (size_t)N_NODES * HDIM;
    ushort_t* x2l = us;                       us += (size_t)N_NODES * HDIM;
    ushort_t* w0ah = us;                      us += IN_DIM * HDIM;              // 32K
    ushort_t* w0al = us;                      us += IN_DIM * HDIM;
    ushort_t* w0bh = us;                      us += HDIM * HDIM;                // 64K
    ushort_t* w0bl = us;                      us += HDIM * HDIM;
    ushort_t* w1ah = us;                      us += HDIM * HDIM;
    ushort_t* w1al = us;                      us += HDIM * HDIM;
    ushort_t* w1bh = us;                      us += HDIM * HDIM;
    ushort_t* w1bl = us;                      us += HDIM * HDIM;
    float* fs = (float*)us;
    float* v  = fs;                           fs += 544;
    float* li = fs;                           fs += N_NODES;
    float* lj = fs;                           fs += N_NODES;
    int* deg    = (int*)fs;
    int* offs   = deg + N_NODES;
    int* cursor = offs + N_NODES + 1;
    int* bucket = cursor + N_NODES;
    float* out = (float*)d_out;

    // ---- CSR build (once, shared by both layers) ----
    hipMemsetAsync(deg, 0, N_NODES * sizeof(int), stream);
    hist_kernel<<<NEDGE / 256, 256, 0, stream>>>(dst, deg);
    build_scan<<<1, 1024, 0, stream>>>(deg, offs, cursor);
    fill_kernel<<<NEDGE / 256, 256, 0, stream>>>(src, dst, cursor, bucket);

    // ---- weight prep (transpose + split) ----
    prep_wsplit<<<(IN_DIM * HDIM + 255) / 256, 256, 0, stream>>>(w0a, IN_DIM, HDIM, w0ah, w0al);
    prep_wsplit<<<(HDIM * HDIM + 255) / 256, 256, 0, stream>>>(w0b, HDIM, HDIM, w0bh, w0bl);
    prep_wsplit<<<(HDIM * HDIM + 255) / 256, 256, 0, stream>>>(w1a, HDIM, HDIM, w1ah, w1al);
    prep_wsplit<<<(HDIM * HDIM + 255) / 256, 256, 0, stream>>>(w1b, HDIM, HDIM, w1bh, w1bl);
    prep_vec<<<1, 256, 0, stream>>>(w_out, b_out, w_edge, b_edge, v);

    dim3 gGemm(N_NODES / 64, HDIM / 64);

    // ---- layer 0 ----
    aggregate128_split<<<N_NODES / 4, 256, 0, stream>>>(x, offs, bucket, h0h, h0l);
    gemm_mfma<IN_DIM><<<gGemm, 256, 0, stream>>>(h0h, h0l, w0ah, w0al, b0a, th_, tl_);
    gemm_mfma<HDIM><<<gGemm, 256, 0, stream>>>(th_, tl_, w0bh, w0bl, b0b, x1h, x1l);

    // ---- layer 1 ----
    aggregate256_split<<<N_NODES / 4, 256, 0, stream>>>(x1h, x1l, offs, bucket, h1h, h1l);
    gemm_mfma<HDIM><<<gGemm, 256, 0, stream>>>(h1h, h1l, w1ah, w1al, b1a, th_, tl_);
    gemm_mfma<HDIM><<<gGemm, 256, 0, stream>>>(th_, tl_, w1bh, w1bl, b1b, x2h, x2l);

    // ---- edge head ----
    lilj_kernel<<<N_NODES / 4, 256, 0, stream>>>(x2h, x2l, v, li, lj);
    edge_out<<<dim3(N_NODES / 4 / 256, N_NODES), 256, 0, stream>>>(li, lj, out);
}